// Round 11
// baseline (258.704 us; speedup 1.0000x reference)
//
#include <hip/hip_runtime.h>
#include <hip/hip_bf16.h>

#define HEADS 16
#define SEQ   2048
#define EMB   1024
#define BATCH 2
#define DHEAD 64
#define MTOK  (BATCH * SEQ)   // 4096

typedef __bf16 bf16x8 __attribute__((ext_vector_type(8)));
typedef float  floatx4 __attribute__((ext_vector_type(4)));

__device__ __forceinline__ void gl_lds16(const void* g, void* l) {
  // async global->LDS, 16B/lane; LDS dest = wave-uniform base + lane*16
  __builtin_amdgcn_global_load_lds((__attribute__((address_space(1))) void*)(g),
                                   (__attribute__((address_space(3))) void*)(l), 16, 0, 0);
}

__device__ __forceinline__ unsigned short f2bf(float f) {
  __bf16 h = (__bf16)f;                      // native cvt, RNE
  return __builtin_bit_cast(unsigned short, h);
}

// ---------------- fp32 -> bf16 conversion (x + 4 weights) ----------------
__global__ __launch_bounds__(256) void cvt_kernel(
    const float* __restrict__ x,  const float* __restrict__ wq,
    const float* __restrict__ wk, const float* __restrict__ wv,
    const float* __restrict__ wu,
    unsigned short* __restrict__ xb,  unsigned short* __restrict__ wqb,
    unsigned short* __restrict__ wkb, unsigned short* __restrict__ wvb,
    unsigned short* __restrict__ wub) {
  const int g = blockIdx.x * 256 + threadIdx.x;  // granule of 4 floats
  const int XG = (MTOK * EMB) / 4;               // 1048576
  const int WG = (EMB * EMB) / 4;                // 262144
  const float* src; unsigned short* dst; int off;
  if (g < XG) { src = x; dst = xb; off = g; }
  else {
    int t = g - XG; int wsel = t / WG; off = t - wsel * WG;
    const float* ss[4] = {wq, wk, wv, wu};
    unsigned short* dd[4] = {wqb, wkb, wvb, wub};
    src = ss[wsel]; dst = dd[wsel];
  }
  float4 v = ((const float4*)src)[off];
  ushort4 o;
  o.x = f2bf(v.x); o.y = f2bf(v.y); o.z = f2bf(v.z); o.w = f2bf(v.w);
  ((ushort4*)dst)[off] = o;
}

// ---------------- FUSED QKV projection: q,k,v = x @ {Wq,Wk,Wv}^T ----------------
// BM=128, BN=64, BK=64 (measured-best config, R5/R6): x staged ONCE per k-iter
// for 3 outputs -> 48 MFMA/wave per barrier.
__global__ __launch_bounds__(256) void gemm_qkv(
    const unsigned short* __restrict__ xb,
    const unsigned short* __restrict__ wqb, const unsigned short* __restrict__ wkb,
    const unsigned short* __restrict__ wvb,
    unsigned short* __restrict__ Qb, unsigned short* __restrict__ Kb,
    unsigned short* __restrict__ Vt) {
  constexpr int BM = 128, BN = 64, BK = 64;
  __shared__ unsigned short As[BM * BK];        // XOR-swizzled rows
  __shared__ unsigned short Bs[3 * BN * BK];
  const int m0 = blockIdx.x * BM, n0 = blockIdx.y * BN;
  const int tid = threadIdx.x, w = tid >> 6, lane = tid & 63;
  const int quad = lane >> 4, l16 = lane & 15;
  const int wm = w >> 1, wn = w & 1;
  const int srow = lane >> 3;
  const int scol = ((lane & 7) ^ srow) * 8;
  const unsigned short* Ws[3] = {wqb, wkb, wvb};

  floatx4 acc[3][4][2] = {};

  for (int kt = 0; kt < EMB / BK; ++kt) {
    const int k0 = kt * BK;
#pragma unroll
    for (int i = 0; i < 4; ++i) {
      int r0 = i * 32 + w * 8;
      gl_lds16(xb + (size_t)(m0 + r0 + srow) * EMB + k0 + scol, &As[r0 * BK]);
    }
#pragma unroll
    for (int z = 0; z < 3; ++z)
#pragma unroll
      for (int i = 0; i < 2; ++i) {
        int r0 = i * 32 + w * 8;
        gl_lds16(Ws[z] + (size_t)(n0 + r0 + srow) * EMB + k0 + scol,
                 &Bs[z * (BN * BK) + r0 * BK]);
      }
    __syncthreads();
#pragma unroll
    for (int ks = 0; ks < 2; ++ks) {
      bf16x8 af[4];
#pragma unroll
      for (int mb = 0; mb < 4; ++mb) {
        int ra = wm * 64 + mb * 16 + l16;
        af[mb] = *(const bf16x8*)&As[ra * BK + (((ks * 4 + quad) ^ (ra & 7)) * 8)];
      }
#pragma unroll
      for (int z = 0; z < 3; ++z) {
        bf16x8 bfv[2];
#pragma unroll
        for (int nb = 0; nb < 2; ++nb) {
          int rb = wn * 32 + nb * 16 + l16;
          bfv[nb] = *(const bf16x8*)&Bs[z * (BN * BK) + rb * BK + (((ks * 4 + quad) ^ (rb & 7)) * 8)];
        }
#pragma unroll
        for (int mb = 0; mb < 4; ++mb)
#pragma unroll
          for (int nb = 0; nb < 2; ++nb)
            acc[z][mb][nb] = __builtin_amdgcn_mfma_f32_16x16x32_bf16(af[mb], bfv[nb], acc[z][mb][nb], 0, 0, 0);
      }
    }
    __syncthreads();
  }

  // ---- epilogue: Q (scaled), K, V^T ----
#pragma unroll
  for (int z = 0; z < 2; ++z) {
    unsigned short* C = (z == 0) ? Qb : Kb;
    const float scale = (z == 0) ? 0.180336876f : 1.0f;  // 0.125*log2(e) folded into Q
#pragma unroll
    for (int mb = 0; mb < 4; ++mb) {
#pragma unroll
      for (int nb = 0; nb < 2; ++nb) {
        int n = n0 + wn * 32 + nb * 16 + l16;
#pragma unroll
        for (int r = 0; r < 4; ++r) {
          int m = m0 + wm * 64 + mb * 16 + quad * 4 + r;
          C[(size_t)m * EMB + n] = f2bf(acc[z][mb][nb][r] * scale);
        }
      }
    }
  }
#pragma unroll
  for (int mb = 0; mb < 4; ++mb) {
    int mbase = m0 + wm * 64 + mb * 16 + quad * 4;
    int b = mbase >> 11, s = mbase & (SEQ - 1);
#pragma unroll
    for (int nb = 0; nb < 2; ++nb) {
      int n = n0 + wn * 32 + nb * 16 + l16;
      ushort4 o;
      o.x = f2bf(acc[2][mb][nb][0]); o.y = f2bf(acc[2][mb][nb][1]);
      o.z = f2bf(acc[2][mb][nb][2]); o.w = f2bf(acc[2][mb][nb][3]);
      *(ushort4*)&Vt[((size_t)b * (HEADS * DHEAD) + n) * SEQ + s] = o;
    }
  }
}

// ---------------- flash-style causal attention, v9: key-split waves ----------------
// Each wave handles a 32-key slice of the 128-key tile for ALL 64 q-rows:
//  - K/V fragments loaded DIRECTLY global->VGPR (each byte read by exactly one
//    wave; L2-local per the XCD swizzle) -> no K/V LDS, no k-loop barriers.
//  - Fixed-shift softmax (exact, R5) -> no per-tile cross-wave communication.
//  - Once per q-tile: O (64x64 f32) + l reduced across waves via LDS atomicAdd.
// Grid (bh=32, pair=16): XCD-local K/V + uniform 17 tiles/block.
__global__ __launch_bounds__(256, 2) void attn_kernel(
    const unsigned short* __restrict__ Qb, const unsigned short* __restrict__ Kb,
    const unsigned short* __restrict__ Vt, unsigned short* __restrict__ ctx) {
  constexpr int PST = 36;                 // P row stride (ushorts): write banks exact-cover
  constexpr int OST = 68;                 // Osum row stride (floats)
  __shared__ unsigned short Ps[4 * 64 * PST];   // per-wave [64 rows][PST]
  __shared__ float Osum[64 * OST];
  __shared__ float Lsum[64];
  const int bh = blockIdx.x, pair = blockIdx.y;
  const int b = bh >> 4, h = bh & 15;
  const int tid = threadIdx.x, w = tid >> 6, lane = tid & 63;
  const int quad = lane >> 4, l16 = lane & 15;

  const unsigned short* Kbh = Kb + (size_t)b * SEQ * EMB + h * DHEAD;
  const unsigned short* Vbh = Vt + (size_t)bh * DHEAD * SEQ;
  unsigned short* Pw = &Ps[w * (64 * PST)];
  const int kw0 = w * 32;                 // this wave's key offset within a tile

  for (int pi = 0; pi < 2; ++pi) {
    const int qt = pi ? (31 - pair) : pair;
    const int q0 = qt * 64;

    __syncthreads();                      // prev readback done before re-zeroing
    for (int i = tid; i < 64 * OST; i += 256) Osum[i] = 0.0f;
    if (tid < 64) Lsum[tid] = 0.0f;
    __syncthreads();

    // Q fragments: rows q0+mb*16+l16, d = ks*32+quad*8 (A-frag, loaded once)
    bf16x8 qf[4][2];
#pragma unroll
    for (int mb = 0; mb < 4; ++mb) {
      const size_t qo = (size_t)(b * SEQ + q0 + mb * 16 + l16) * EMB + h * DHEAD;
#pragma unroll
      for (int ks = 0; ks < 2; ++ks)
        qf[mb][ks] = *(const bf16x8*)&Qb[qo + ks * 32 + quad * 8];
    }

    float lsum[4][4] = {};
    floatx4 acc_o[4][4] = {};

    const int nkt = (qt + 2) >> 1;        // ceil((qt+1)*64/128)
    for (int kt = 0; kt < nkt; ++kt) {
      const int k0 = kt * 128 + kw0;      // this wave's 32 keys start
      // ---- K/V fragments: direct global->VGPR (B-frag: n=l16, k=quad*8+j) ----
      bf16x8 kf[2][2], vf[4];
#pragma unroll
      for (int nb = 0; nb < 2; ++nb) {
        const size_t ko = (size_t)(k0 + nb * 16 + l16) * EMB + quad * 8;
#pragma unroll
        for (int ks = 0; ks < 2; ++ks)
          kf[nb][ks] = *(const bf16x8*)&Kbh[ko + ks * 32];
      }
#pragma unroll
      for (int nbv = 0; nbv < 4; ++nbv)
        vf[nbv] = *(const bf16x8*)&Vbh[(size_t)(nbv * 16 + l16) * SEQ + k0 + quad * 8];

      // ---- S = Q K^T : 64 rows x 32 keys ----
      floatx4 accs[4][2] = {};
#pragma unroll
      for (int ks = 0; ks < 2; ++ks)
#pragma unroll
        for (int mb = 0; mb < 4; ++mb)
#pragma unroll
          for (int nb = 0; nb < 2; ++nb)
            accs[mb][nb] = __builtin_amdgcn_mfma_f32_16x16x32_bf16(qf[mb][ks], kf[nb][ks], accs[mb][nb], 0, 0, 0);

      // ---- causal mask (final tile only) ----
      if (kt == nkt - 1) {
#pragma unroll
        for (int mb = 0; mb < 4; ++mb)
#pragma unroll
          for (int nb = 0; nb < 2; ++nb) {
            int key = k0 + nb * 16 + l16;
#pragma unroll
            for (int r = 0; r < 4; ++r)
              if (key > q0 + mb * 16 + quad * 4 + r) accs[mb][nb][r] = -1e30f;
          }
      }

      // ---- p = exp2(s) (fixed shift), accumulate l, stash P (wave-private) ----
#pragma unroll
      for (int mb = 0; mb < 4; ++mb)
#pragma unroll
        for (int r = 0; r < 4; ++r) {
          float p0 = exp2f(accs[mb][0][r]);
          float p1 = exp2f(accs[mb][1][r]);
          lsum[mb][r] += p0 + p1;
          int rowoff = (mb * 16 + quad * 4 + r) * PST + l16;
          Pw[rowoff]      = f2bf(p0);
          Pw[rowoff + 16] = f2bf(p1);
        }

      // ---- O += P V^T : A = P[row][key] (m=l16), B = V^T[d][key] (n=l16) ----
#pragma unroll
      for (int mb = 0; mb < 4; ++mb) {
        bf16x8 pf = *(const bf16x8*)&Pw[(mb * 16 + l16) * PST + quad * 8];
#pragma unroll
        for (int nbv = 0; nbv < 4; ++nbv)
          acc_o[mb][nbv] = __builtin_amdgcn_mfma_f32_16x16x32_bf16(pf, vf[nbv], acc_o[mb][nbv], 0, 0, 0);
      }
    }

    // ---- cross-wave O reduction (once per q-tile) ----
#pragma unroll
    for (int mb = 0; mb < 4; ++mb)
#pragma unroll
      for (int nbv = 0; nbv < 4; ++nbv)
#pragma unroll
        for (int r = 0; r < 4; ++r)
          atomicAdd(&Osum[(mb * 16 + quad * 4 + r) * OST + nbv * 16 + l16], acc_o[mb][nbv][r]);
    // ---- cross-wave l reduction ----
#pragma unroll
    for (int mb = 0; mb < 4; ++mb)
#pragma unroll
      for (int r = 0; r < 4; ++r) {
        float rs = lsum[mb][r];
        rs += __shfl_xor(rs, 1);
        rs += __shfl_xor(rs, 2);
        rs += __shfl_xor(rs, 4);
        rs += __shfl_xor(rs, 8);
        if (l16 == 0) atomicAdd(&Lsum[mb * 16 + quad * 4 + r], rs);
      }
    __syncthreads();

    // ---- readback + normalize + store: wave w owns rows w*16+l16 ----
    {
      const int row = w * 16 + l16;
      const float inv = 1.0f / Lsum[row];
      float v[16];
#pragma unroll
      for (int i = 0; i < 4; ++i) {
        float4 f4 = *(const float4*)&Osum[row * OST + quad * 16 + i * 4];
        v[i * 4 + 0] = f4.x; v[i * 4 + 1] = f4.y; v[i * 4 + 2] = f4.z; v[i * 4 + 3] = f4.w;
      }
      unsigned short o[16];
#pragma unroll
      for (int i = 0; i < 16; ++i) o[i] = f2bf(v[i] * inv);
      const size_t base = (size_t)(b * SEQ + q0 + row) * EMB + h * DHEAD + quad * 16;
      *(ushort4*)&ctx[base]      = *(ushort4*)&o[0];
      *(ushort4*)&ctx[base + 4]  = *(ushort4*)&o[4];
      *(ushort4*)&ctx[base + 8]  = *(ushort4*)&o[8];
      *(ushort4*)&ctx[base + 12] = *(ushort4*)&o[12];
    }
  }
}

// ---------------- output projection: out = ctx @ Wu^T + bu (fp32 out) ----------------
// 128x64 tile, BK=64 swizzled (measured-best); wave tile 64x32 (4x2 MFMA grid).
__global__ __launch_bounds__(256) void gemm_out(
    const unsigned short* __restrict__ ctx, const unsigned short* __restrict__ wub,
    const float* __restrict__ bu, float* __restrict__ out) {
  constexpr int BM = 128, BN = 64, BK = 64;
  __shared__ unsigned short As[BM * BK];
  __shared__ unsigned short Bs[BN * BK];
  const int m0 = blockIdx.x * BM, n0 = blockIdx.y * BN;
  const int tid = threadIdx.x, w = tid >> 6, lane = tid & 63;
  const int quad = lane >> 4, l16 = lane & 15;
  const int wm = w >> 1, wn = w & 1;
  const int srow = lane >> 3;
  const int scol = ((lane & 7) ^ srow) * 8;

  floatx4 acc[4][2] = {};

  for (int kt = 0; kt < EMB / BK; ++kt) {
    const int k0 = kt * BK;
#pragma unroll
    for (int i = 0; i < 4; ++i) {
      int r0 = i * 32 + w * 8;
      gl_lds16(ctx + (size_t)(m0 + r0 + srow) * EMB + k0 + scol, &As[r0 * BK]);
    }
#pragma unroll
    for (int i = 0; i < 2; ++i) {
      int r0 = i * 32 + w * 8;
      gl_lds16(wub + (size_t)(n0 + r0 + srow) * EMB + k0 + scol, &Bs[r0 * BK]);
    }
    __syncthreads();
    bf16x8 af[4][2], bfv[2][2];
#pragma unroll
    for (int mb = 0; mb < 4; ++mb) {
      int ra = wm * 64 + mb * 16 + l16;
#pragma unroll
      for (int ks = 0; ks < 2; ++ks)
        af[mb][ks] = *(const bf16x8*)&As[ra * BK + (((ks * 4 + quad) ^ (ra & 7)) * 8)];
    }
#pragma unroll
    for (int nb = 0; nb < 2; ++nb) {
      int rb = wn * 32 + nb * 16 + l16;
#pragma unroll
      for (int ks = 0; ks < 2; ++ks)
        bfv[nb][ks] = *(const bf16x8*)&Bs[rb * BK + (((ks * 4 + quad) ^ (rb & 7)) * 8)];
    }
#pragma unroll
    for (int ks = 0; ks < 2; ++ks)
#pragma unroll
      for (int mb = 0; mb < 4; ++mb)
#pragma unroll
        for (int nb = 0; nb < 2; ++nb)
          acc[mb][nb] = __builtin_amdgcn_mfma_f32_16x16x32_bf16(af[mb][ks], bfv[nb][ks], acc[mb][nb], 0, 0, 0);
    __syncthreads();
  }

#pragma unroll
  for (int mb = 0; mb < 4; ++mb) {
#pragma unroll
    for (int nb = 0; nb < 2; ++nb) {
      int n = n0 + wn * 32 + nb * 16 + l16;
      float bias = bu[n];
#pragma unroll
      for (int r = 0; r < 4; ++r) {
        int m = m0 + wm * 64 + mb * 16 + quad * 4 + r;
        out[(size_t)m * EMB + n] = acc[mb][nb][r] + bias;
      }
    }
  }
}

extern "C" void kernel_launch(void* const* d_in, const int* in_sizes, int n_in,
                              void* d_out, int out_size, void* d_ws, size_t ws_size,
                              hipStream_t stream) {
  // setup_inputs order: x, Wk, Wq, Wv, Wu, bu
  const float* x  = (const float*)d_in[0];
  const float* Wk = (const float*)d_in[1];
  const float* Wq = (const float*)d_in[2];
  const float* Wv = (const float*)d_in[3];
  const float* Wu = (const float*)d_in[4];
  const float* bu = (const float*)d_in[5];

  char* ws = (char*)d_ws;
  const size_t MB1 = 1 << 20;
  unsigned short* xb  = (unsigned short*)(ws + 0);
  unsigned short* wqb = (unsigned short*)(ws + 8  * MB1);
  unsigned short* wkb = (unsigned short*)(ws + 10 * MB1);
  unsigned short* wvb = (unsigned short*)(ws + 12 * MB1);
  unsigned short* wub = (unsigned short*)(ws + 14 * MB1);
  unsigned short* Qb  = (unsigned short*)(ws + 16 * MB1);
  unsigned short* Kb  = (unsigned short*)(ws + 24 * MB1);
  unsigned short* Vt  = (unsigned short*)(ws + 32 * MB1);
  unsigned short* ctx = (unsigned short*)(ws + 40 * MB1);

  cvt_kernel<<<8192, 256, 0, stream>>>(x, Wq, Wk, Wv, Wu, xb, wqb, wkb, wvb, wub);
  gemm_qkv<<<dim3(32, 16), 256, 0, stream>>>(xb, wqb, wkb, wvb, Qb, Kb, Vt);
  attn_kernel<<<dim3(32, 16), 256, 0, stream>>>(Qb, Kb, Vt, ctx);
  gemm_out<<<dim3(32, 16), 256, 0, stream>>>(ctx, wub, bu, (float*)d_out);
}